// Round 1
// baseline (961.877 us; speedup 1.0000x reference)
//
#include <hip/hip_runtime.h>

typedef unsigned short u16;
typedef __bf16 bf16x8 __attribute__((ext_vector_type(8)));
typedef u16 u16x8 __attribute__((ext_vector_type(8)));
typedef float floatx4 __attribute__((ext_vector_type(4)));

#define DEV __device__ __forceinline__

DEV u16 f2bf(float f) {
  unsigned u = __builtin_bit_cast(unsigned, f);
  unsigned r = (u + 0x7FFFu + ((u >> 16) & 1u)) >> 16;  // RNE
  return (u16)r;
}
DEV float bf2f(u16 h) {
  unsigned u = ((unsigned)h) << 16;
  return __builtin_bit_cast(float, u);
}

typedef __attribute__((address_space(3))) void lds_void_t;
typedef const __attribute__((address_space(1))) void gbl_void_t;

DEV void async16(const void* g, void* l) {
  __builtin_amdgcn_global_load_lds((gbl_void_t*)g, (lds_void_t*)l, 16, 0, 0);
}

// ---------------- elementwise converts ----------------

__global__ __launch_bounds__(256) void k_split32(const float* __restrict__ x,
                                                 u16* __restrict__ hi,
                                                 u16* __restrict__ lo, int n4) {
  int i = blockIdx.x * 256 + threadIdx.x;
  if (i >= n4) return;
  float4 v = ((const float4*)x)[i];
  u16 h0 = f2bf(v.x), h1 = f2bf(v.y), h2 = f2bf(v.z), h3 = f2bf(v.w);
  *(ushort4*)&hi[4 * (size_t)i] = make_ushort4(h0, h1, h2, h3);
  *(ushort4*)&lo[4 * (size_t)i] =
      make_ushort4(f2bf(v.x - bf2f(h0)), f2bf(v.y - bf2f(h1)),
                   f2bf(v.z - bf2f(h2)), f2bf(v.w - bf2f(h3)));
}

__global__ __launch_bounds__(256) void k_cvt32(const float* __restrict__ x,
                                               u16* __restrict__ o, int n4) {
  int i = blockIdx.x * 256 + threadIdx.x;
  if (i >= n4) return;
  float4 v = ((const float4*)x)[i];
  *(ushort4*)&o[4 * (size_t)i] =
      make_ushort4(f2bf(v.x), f2bf(v.y), f2bf(v.z), f2bf(v.w));
}

// ---------------- bf16 transpose (R x C -> C x R) ----------------

__global__ __launch_bounds__(256) void k_transpose(const u16* __restrict__ in,
                                                   u16* __restrict__ out,
                                                   int R, int C) {
  __shared__ u16 T[64][72];
  int m0 = blockIdx.x * 64;
  int n0 = blockIdx.y * 64;
  int t = threadIdx.x;
#pragma unroll
  for (int i = 0; i < 2; ++i) {
    int lin = i * 2048 + t * 8;
    int r = lin >> 6, c = lin & 63;
    u16x8 d = *(const u16x8*)&in[(size_t)(m0 + r) * C + n0 + c];
#pragma unroll
    for (int j = 0; j < 8; ++j) T[r][c + j] = d[j];
  }
  __syncthreads();
#pragma unroll
  for (int i = 0; i < 2; ++i) {
    int lin = i * 2048 + t * 8;
    int r = lin >> 6, c = lin & 63;  // r = out-row in tile (orig col)
    u16x8 d;
#pragma unroll
    for (int j = 0; j < 8; ++j) d[j] = T[c + j][r];
    *(u16x8*)&out[(size_t)(n0 + r) * R + m0 + c] = d;
  }
}

// ---------------- in-place row softmax over 8192 cols ----------------

__global__ __launch_bounds__(256) void k_softmax(float* __restrict__ W) {
  const size_t row = blockIdx.x;
  float4* pv = (float4*)(W + row * 8192);
  const int t = threadIdx.x;
  const int w = t >> 6, l = t & 63;
  float4 v[8];
#pragma unroll
  for (int i = 0; i < 8; ++i) v[i] = pv[i * 256 + t];
  float m = -1e30f;
#pragma unroll
  for (int i = 0; i < 8; ++i) {
    m = fmaxf(m, fmaxf(fmaxf(v[i].x, v[i].y), fmaxf(v[i].z, v[i].w)));
  }
#pragma unroll
  for (int o = 32; o >= 1; o >>= 1) m = fmaxf(m, __shfl_xor(m, o, 64));
  __shared__ float redm[4];
  __shared__ float reds[4];
  if (l == 0) redm[w] = m;
  __syncthreads();
  m = fmaxf(fmaxf(redm[0], redm[1]), fmaxf(redm[2], redm[3]));
  float s = 0.f;
#pragma unroll
  for (int i = 0; i < 8; ++i) {
    v[i].x = __expf(v[i].x - m); s += v[i].x;
    v[i].y = __expf(v[i].y - m); s += v[i].y;
    v[i].z = __expf(v[i].z - m); s += v[i].z;
    v[i].w = __expf(v[i].w - m); s += v[i].w;
  }
#pragma unroll
  for (int o = 32; o >= 1; o >>= 1) s += __shfl_xor(s, o, 64);
  if (l == 0) reds[w] = s;
  __syncthreads();
  s = (reds[0] + reds[1]) + (reds[2] + reds[3]);
  float inv = 1.0f / s;
#pragma unroll
  for (int i = 0; i < 8; ++i) {
    v[i].x *= inv; v[i].y *= inv; v[i].z *= inv; v[i].w *= inv;
    pv[i * 256 + t] = v[i];
  }
}

// ---------------- GEMM: C[M,N] = A[M,K] * B[N,K]^T (+bias) ----------------
// 128x128 tile, 4 waves of 64x64, mfma_f32_16x16x32_bf16, BK=32.
// SPLIT: A,B given as hi/lo bf16 pairs; 3-pass (hh+hl+lh) for ~fp32 accuracy.
// AF32:  A is fp32, converted to bf16 while staging to LDS.
// OMODE: 0 = f32 out, 1 = bf16 out, 2 = split hi/lo bf16 out.

template <bool SPLIT, bool AF32, int OMODE, bool BIAS>
__global__ __launch_bounds__(256, 2)
void k_gemm(const void* Ah_, const void* Al_, const u16* __restrict__ Bh,
            const u16* __restrict__ Bl, const float* __restrict__ bias,
            void* C0_, void* C1_, int K, int lda, int ldb, int ldc) {
  constexpr int LDSN = 128 * 32;
  __shared__ alignas(16) u16 Ash[LDSN];
  __shared__ alignas(16) u16 Bsh[LDSN];
  __shared__ alignas(16) u16 Asl[SPLIT ? LDSN : 8];
  __shared__ alignas(16) u16 Bsl[SPLIT ? LDSN : 8];

  const int m0 = blockIdx.x * 128;
  const int n0 = blockIdx.y * 128;
  const int tid = threadIdx.x;
  const int w = tid >> 6;
  const int l = tid & 63;
  const int lr = l & 15;
  const int lq = l >> 4;
  const int wr = (w >> 1) * 64;
  const int wc = (w & 1) * 64;
  const int srow = l >> 2;        // 0..15 within 16-row chunk
  const int scol = (l & 3) * 8;   // 0,8,16,24

  const u16* Ah = (const u16*)Ah_;
  const u16* Al = (const u16*)Al_;
  const float* Af = (const float*)Ah_;

  floatx4 acc[4][4] = {};

  for (int k0 = 0; k0 < K; k0 += 32) {
    __syncthreads();
    if constexpr (!AF32) {
#pragma unroll
      for (int i = 0; i < 2; ++i) {
        int c = w * 2 + i;
        int row = c * 16 + srow;
        async16(Ah + (size_t)(m0 + row) * lda + k0 + scol, &Ash[c * 512]);
        if constexpr (SPLIT)
          async16(Al + (size_t)(m0 + row) * lda + k0 + scol, &Asl[c * 512]);
      }
    } else {
#pragma unroll
      for (int i = 0; i < 2; ++i) {
        int lin = i * 2048 + tid * 8;
        int row = lin >> 5, col = lin & 31;
        const float* g = Af + (size_t)(m0 + row) * lda + k0 + col;
        float4 u0 = *(const float4*)g;
        float4 u1 = *(const float4*)(g + 4);
        u16x8 tv;
        tv[0] = f2bf(u0.x); tv[1] = f2bf(u0.y); tv[2] = f2bf(u0.z); tv[3] = f2bf(u0.w);
        tv[4] = f2bf(u1.x); tv[5] = f2bf(u1.y); tv[6] = f2bf(u1.z); tv[7] = f2bf(u1.w);
        *(u16x8*)&Ash[lin] = tv;
      }
    }
#pragma unroll
    for (int i = 0; i < 2; ++i) {
      int c = w * 2 + i;
      int row = c * 16 + srow;
      async16(Bh + (size_t)(n0 + row) * ldb + k0 + scol, &Bsh[c * 512]);
      if constexpr (SPLIT)
        async16(Bl + (size_t)(n0 + row) * ldb + k0 + scol, &Bsl[c * 512]);
    }
    __syncthreads();

    bf16x8 fah[4], fbh[4];
#pragma unroll
    for (int t = 0; t < 4; ++t) {
      fah[t] = *(const bf16x8*)&Ash[(wr + t * 16 + lr) * 32 + lq * 8];
      fbh[t] = *(const bf16x8*)&Bsh[(wc + t * 16 + lr) * 32 + lq * 8];
    }
    if constexpr (SPLIT) {
      bf16x8 fal[4], fbl[4];
#pragma unroll
      for (int t = 0; t < 4; ++t) {
        fal[t] = *(const bf16x8*)&Asl[(wr + t * 16 + lr) * 32 + lq * 8];
        fbl[t] = *(const bf16x8*)&Bsl[(wc + t * 16 + lr) * 32 + lq * 8];
      }
#pragma unroll
      for (int mt = 0; mt < 4; ++mt)
#pragma unroll
        for (int nt = 0; nt < 4; ++nt)
          acc[mt][nt] = __builtin_amdgcn_mfma_f32_16x16x32_bf16(
              fah[mt], fbh[nt], acc[mt][nt], 0, 0, 0);
#pragma unroll
      for (int mt = 0; mt < 4; ++mt)
#pragma unroll
        for (int nt = 0; nt < 4; ++nt)
          acc[mt][nt] = __builtin_amdgcn_mfma_f32_16x16x32_bf16(
              fah[mt], fbl[nt], acc[mt][nt], 0, 0, 0);
#pragma unroll
      for (int mt = 0; mt < 4; ++mt)
#pragma unroll
        for (int nt = 0; nt < 4; ++nt)
          acc[mt][nt] = __builtin_amdgcn_mfma_f32_16x16x32_bf16(
              fal[mt], fbh[nt], acc[mt][nt], 0, 0, 0);
    } else {
#pragma unroll
      for (int mt = 0; mt < 4; ++mt)
#pragma unroll
        for (int nt = 0; nt < 4; ++nt)
          acc[mt][nt] = __builtin_amdgcn_mfma_f32_16x16x32_bf16(
              fah[mt], fbh[nt], acc[mt][nt], 0, 0, 0);
    }
  }

  float bv[4] = {0.f, 0.f, 0.f, 0.f};
  if constexpr (BIAS) {
#pragma unroll
    for (int nt = 0; nt < 4; ++nt) bv[nt] = bias[n0 + wc + nt * 16 + lr];
  }
#pragma unroll
  for (int mt = 0; mt < 4; ++mt)
#pragma unroll
    for (int nt = 0; nt < 4; ++nt)
#pragma unroll
      for (int r = 0; r < 4; ++r) {
        float x = acc[mt][nt][r] + bv[nt];
        int row = m0 + wr + mt * 16 + lq * 4 + r;
        int col = n0 + wc + nt * 16 + lr;
        size_t idx = (size_t)row * ldc + col;
        if constexpr (OMODE == 0) {
          ((float*)C0_)[idx] = x;
        } else if constexpr (OMODE == 1) {
          ((u16*)C0_)[idx] = f2bf(x);
        } else {
          u16 h = f2bf(x);
          ((u16*)C0_)[idx] = h;
          ((u16*)C1_)[idx] = f2bf(x - bf2f(h));
        }
      }
}

// ---------------- launch ----------------

extern "C" void kernel_launch(void* const* d_in, const int* in_sizes, int n_in,
                              void* d_out, int out_size, void* d_ws,
                              size_t ws_size, hipStream_t stream) {
  constexpr int N = 8192, H = 512;
  const float* q   = (const float*)d_in[0];
  const float* kin = (const float*)d_in[1];
  const float* v   = (const float*)d_in[2];
  const float* Wq  = (const float*)d_in[3];
  const float* bq  = (const float*)d_in[4];
  const float* Wk  = (const float*)d_in[5];
  const float* bk  = (const float*)d_in[6];
  const float* Wv  = (const float*)d_in[7];
  const float* bv  = (const float*)d_in[8];
  const float* Wo  = (const float*)d_in[9];
  const float* bo  = (const float*)d_in[10];
  float* out  = (float*)d_out;
  float* norm = out + (size_t)N * H;  // [N,N] normalized region

  char* ws = (char*)d_ws;
  const size_t MB = 1024 * 1024;
  u16* xin_hi = (u16*)(ws + 0 * MB);           // 8 MB  (also reused as out0)
  u16* xin_lo = (u16*)(ws + 8 * MB);           // 8 MB  (also reused as vp)
  u16* w_hi   = (u16*)(ws + 16 * MB);          // 0.5 MB
  u16* w_lo   = (u16*)(ws + 16 * MB + 512 * 1024);
  u16* qp_hi  = (u16*)(ws + 17 * MB);
  u16* qp_lo  = (u16*)(ws + 25 * MB);
  u16* kp_hi  = (u16*)(ws + 33 * MB);
  u16* kp_lo  = (u16*)(ws + 41 * MB);
  u16* vpT    = (u16*)(ws + 49 * MB);          // [H][N] bf16
  u16* vp     = xin_lo;                        // [N][H] bf16
  u16* out0   = xin_hi;                        // [N][H] bf16

  dim3 blk(256);

  // q projection (split precision)
  k_split32<<<4096, blk, 0, stream>>>(q, xin_hi, xin_lo, (N * H) / 4);
  k_split32<<<256, blk, 0, stream>>>(Wq, w_hi, w_lo, (H * H) / 4);
  k_gemm<true, false, 2, true><<<dim3(64, 4), blk, 0, stream>>>(
      xin_hi, xin_lo, w_hi, w_lo, bq, qp_hi, qp_lo, H, H, H, H);

  // k projection (split precision)
  k_split32<<<4096, blk, 0, stream>>>(kin, xin_hi, xin_lo, (N * H) / 4);
  k_split32<<<256, blk, 0, stream>>>(Wk, w_hi, w_lo, (H * H) / 4);
  k_gemm<true, false, 2, true><<<dim3(64, 4), blk, 0, stream>>>(
      xin_hi, xin_lo, w_hi, w_lo, bk, kp_hi, kp_lo, H, H, H, H);

  // v projection (plain bf16) -> vp, then transpose -> vpT
  k_cvt32<<<4096, blk, 0, stream>>>(v, xin_hi, (N * H) / 4);
  k_cvt32<<<256, blk, 0, stream>>>(Wv, w_hi, (H * H) / 4);
  k_gemm<false, false, 1, true><<<dim3(64, 4), blk, 0, stream>>>(
      xin_hi, nullptr, w_hi, nullptr, bv, vp, nullptr, H, H, H, H);
  k_transpose<<<dim3(128, 8), blk, 0, stream>>>(vp, vpT, N, H);

  // logits = qp @ kp^T (split precision, fp32 out into normalized region)
  k_gemm<true, false, 0, false><<<dim3(64, 64), blk, 0, stream>>>(
      qp_hi, qp_lo, kp_hi, kp_lo, nullptr, norm, nullptr, H, H, H, N);

  // softmax rows in place
  k_softmax<<<N, blk, 0, stream>>>(norm);

  // out0 = normalized @ vp   (A fp32 on-the-fly cvt, B = vpT)
  k_gemm<false, true, 1, false><<<dim3(64, 4), blk, 0, stream>>>(
      norm, nullptr, vpT, nullptr, nullptr, out0, nullptr, N, N, N, H);

  // out = out0 @ Wo^T + bo
  k_cvt32<<<256, blk, 0, stream>>>(Wo, w_hi, (H * H) / 4);
  k_gemm<false, false, 0, true><<<dim3(64, 4), blk, 0, stream>>>(
      out0, nullptr, w_hi, nullptr, bo, out, nullptr, H, H, H, H);
}

// Round 2
// 724.204 us; speedup vs baseline: 1.3282x; 1.3282x over previous
//
#include <hip/hip_runtime.h>

typedef unsigned short u16;
typedef _Float16 f16x8 __attribute__((ext_vector_type(8)));
typedef u16 u16x8 __attribute__((ext_vector_type(8)));
typedef float floatx4 __attribute__((ext_vector_type(4)));

#define DEV __device__ __forceinline__

DEV u16 f2h(float f) {
  _Float16 h = (_Float16)f;  // RNE
  return __builtin_bit_cast(u16, h);
}

typedef __attribute__((address_space(3))) void lds_void_t;
typedef const __attribute__((address_space(1))) void gbl_void_t;

DEV void async16(const void* g, void* l) {
  __builtin_amdgcn_global_load_lds((gbl_void_t*)g, (lds_void_t*)l, 16, 0, 0);
}

// ---------------- fp32 -> fp16 convert ----------------

__global__ __launch_bounds__(256) void k_cvt16(const float* __restrict__ x,
                                               u16* __restrict__ o, int n4) {
  int i = blockIdx.x * 256 + threadIdx.x;
  if (i >= n4) return;
  float4 v = ((const float4*)x)[i];
  *(ushort4*)&o[4 * (size_t)i] =
      make_ushort4(f2h(v.x), f2h(v.y), f2h(v.z), f2h(v.w));
}

// ---------------- 16-bit transpose (R x C -> C x R) ----------------

__global__ __launch_bounds__(256) void k_transpose(const u16* __restrict__ in,
                                                   u16* __restrict__ out,
                                                   int R, int C) {
  __shared__ u16 T[64][72];
  int m0 = blockIdx.x * 64;
  int n0 = blockIdx.y * 64;
  int t = threadIdx.x;
#pragma unroll
  for (int i = 0; i < 2; ++i) {
    int lin = i * 2048 + t * 8;
    int r = lin >> 6, c = lin & 63;
    u16x8 d = *(const u16x8*)&in[(size_t)(m0 + r) * C + n0 + c];
#pragma unroll
    for (int j = 0; j < 8; ++j) T[r][c + j] = d[j];
  }
  __syncthreads();
#pragma unroll
  for (int i = 0; i < 2; ++i) {
    int lin = i * 2048 + t * 8;
    int r = lin >> 6, c = lin & 63;
    u16x8 d;
#pragma unroll
    for (int j = 0; j < 8; ++j) d[j] = T[c + j][r];
    *(u16x8*)&out[(size_t)(n0 + r) * R + m0 + c] = d;
  }
}

// ---------------- in-place row softmax over 8192 cols (+opt fp16 copy) ----

template <bool WRITEP>
__global__ __launch_bounds__(256) void k_softmax(float* __restrict__ W,
                                                 u16* __restrict__ P) {
  const size_t row = blockIdx.x;
  float4* pv = (float4*)(W + row * 8192);
  const int t = threadIdx.x;
  const int w = t >> 6, l = t & 63;
  float4 v[8];
#pragma unroll
  for (int i = 0; i < 8; ++i) v[i] = pv[i * 256 + t];
  float m = -1e30f;
#pragma unroll
  for (int i = 0; i < 8; ++i)
    m = fmaxf(m, fmaxf(fmaxf(v[i].x, v[i].y), fmaxf(v[i].z, v[i].w)));
#pragma unroll
  for (int o = 32; o >= 1; o >>= 1) m = fmaxf(m, __shfl_xor(m, o, 64));
  __shared__ float redm[4];
  __shared__ float reds[4];
  if (l == 0) redm[w] = m;
  __syncthreads();
  m = fmaxf(fmaxf(redm[0], redm[1]), fmaxf(redm[2], redm[3]));
  float s = 0.f;
#pragma unroll
  for (int i = 0; i < 8; ++i) {
    v[i].x = __expf(v[i].x - m); s += v[i].x;
    v[i].y = __expf(v[i].y - m); s += v[i].y;
    v[i].z = __expf(v[i].z - m); s += v[i].z;
    v[i].w = __expf(v[i].w - m); s += v[i].w;
  }
#pragma unroll
  for (int o = 32; o >= 1; o >>= 1) s += __shfl_xor(s, o, 64);
  if (l == 0) reds[w] = s;
  __syncthreads();
  s = (reds[0] + reds[1]) + (reds[2] + reds[3]);
  float inv = 1.0f / s;
#pragma unroll
  for (int i = 0; i < 8; ++i) {
    v[i].x *= inv; v[i].y *= inv; v[i].z *= inv; v[i].w *= inv;
    pv[i * 256 + t] = v[i];
    if constexpr (WRITEP) {
      *(ushort4*)&P[row * 8192 + (size_t)(i * 256 + t) * 4] =
          make_ushort4(f2h(v[i].x), f2h(v[i].y), f2h(v[i].z), f2h(v[i].w));
    }
  }
}

// ---------------- GEMM: C[M,N] = A[M,K] * B[N,K]^T (+bias), fp16 ----------
// 128xBN tile, 4 waves (2x2), mfma_f32_16x16x32_f16, BK=32.
// AF32: A is fp32, converted to fp16 while staging to LDS.
// OMODE: 0 = f32 out, 1 = fp16 out.

template <int BN, bool AF32, int OMODE, bool BIAS>
__global__ __launch_bounds__(256, 2)
void k_gemm(const void* A_, const u16* __restrict__ Bh,
            const float* __restrict__ bias, void* C_, int K, int lda, int ldb,
            int ldc) {
  constexpr int NT = BN / 32;      // wave col-tiles (4 or 2)
  constexpr int BCHW = BN / 64;    // B 16-row chunks per wave (2 or 1)
  __shared__ alignas(16) u16 Ash[128 * 32];
  __shared__ alignas(16) u16 Bsh[BN * 32];

  const int m0 = blockIdx.x * 128;
  const int n0 = blockIdx.y * BN;
  const int tid = threadIdx.x;
  const int w = tid >> 6;
  const int l = tid & 63;
  const int lr = l & 15;
  const int lq = l >> 4;
  const int wr = (w >> 1) * 64;
  const int wc = (w & 1) * (BN / 2);
  const int srow = l >> 2;       // 0..15 within a 16-row chunk
  const int scol = (l & 3) * 8;  // 0,8,16,24

  const u16* Ah = (const u16*)A_;
  const float* Af = (const float*)A_;

  floatx4 acc[4][NT] = {};

  for (int k0 = 0; k0 < K; k0 += 32) {
    __syncthreads();
    if constexpr (!AF32) {
#pragma unroll
      for (int i = 0; i < 2; ++i) {
        int c = w * 2 + i;
        int row = c * 16 + srow;
        async16(Ah + (size_t)(m0 + row) * lda + k0 + scol, &Ash[c * 512]);
      }
    } else {
#pragma unroll
      for (int i = 0; i < 2; ++i) {
        int lin = i * 2048 + tid * 8;
        int row = lin >> 5, col = lin & 31;
        const float* g = Af + (size_t)(m0 + row) * lda + k0 + col;
        float4 u0 = *(const float4*)g;
        float4 u1 = *(const float4*)(g + 4);
        u16x8 tv;
        tv[0] = f2h(u0.x); tv[1] = f2h(u0.y); tv[2] = f2h(u0.z); tv[3] = f2h(u0.w);
        tv[4] = f2h(u1.x); tv[5] = f2h(u1.y); tv[6] = f2h(u1.z); tv[7] = f2h(u1.w);
        *(u16x8*)&Ash[lin] = tv;
      }
    }
#pragma unroll
    for (int i = 0; i < BCHW; ++i) {
      int c = w * BCHW + i;
      int row = c * 16 + srow;
      async16(Bh + (size_t)(n0 + row) * ldb + k0 + scol, &Bsh[c * 512]);
    }
    __syncthreads();

    f16x8 fa[4], fb[NT];
#pragma unroll
    for (int t = 0; t < 4; ++t)
      fa[t] = *(const f16x8*)&Ash[(wr + t * 16 + lr) * 32 + lq * 8];
#pragma unroll
    for (int t = 0; t < NT; ++t)
      fb[t] = *(const f16x8*)&Bsh[(wc + t * 16 + lr) * 32 + lq * 8];
#pragma unroll
    for (int mt = 0; mt < 4; ++mt)
#pragma unroll
      for (int nt = 0; nt < NT; ++nt)
        acc[mt][nt] = __builtin_amdgcn_mfma_f32_16x16x32_f16(
            fa[mt], fb[nt], acc[mt][nt], 0, 0, 0);
  }

  float bv[NT];
#pragma unroll
  for (int nt = 0; nt < NT; ++nt)
    bv[nt] = BIAS ? bias[n0 + wc + nt * 16 + lr] : 0.f;
#pragma unroll
  for (int mt = 0; mt < 4; ++mt)
#pragma unroll
    for (int nt = 0; nt < NT; ++nt)
#pragma unroll
      for (int r = 0; r < 4; ++r) {
        float x = acc[mt][nt][r] + bv[nt];
        int row = m0 + wr + mt * 16 + lq * 4 + r;
        int col = n0 + wc + nt * 16 + lr;
        size_t idx = (size_t)row * ldc + col;
        if constexpr (OMODE == 0) {
          ((float*)C_)[idx] = x;
        } else {
          ((u16*)C_)[idx] = f2h(x);
        }
      }
}

// ---------------- launch ----------------

extern "C" void kernel_launch(void* const* d_in, const int* in_sizes, int n_in,
                              void* d_out, int out_size, void* d_ws,
                              size_t ws_size, hipStream_t stream) {
  constexpr int N = 8192, H = 512;
  const float* q   = (const float*)d_in[0];
  const float* kin = (const float*)d_in[1];
  const float* v   = (const float*)d_in[2];
  const float* Wq  = (const float*)d_in[3];
  const float* bq  = (const float*)d_in[4];
  const float* Wk  = (const float*)d_in[5];
  const float* bk  = (const float*)d_in[6];
  const float* Wv  = (const float*)d_in[7];
  const float* bv  = (const float*)d_in[8];
  const float* Wo  = (const float*)d_in[9];
  const float* bo  = (const float*)d_in[10];
  float* out  = (float*)d_out;
  float* norm = out + (size_t)N * H;  // [N,N] normalized region

  char* ws = (char*)d_ws;
  const size_t MB = 1024 * 1024;
  u16* xh   = (u16*)(ws + 0 * MB);    // 8 MB input fp16 (q/k/v serially)
  u16* wb   = (u16*)(ws + 8 * MB);    // 0.5 MB weight fp16
  u16* qp   = (u16*)(ws + 9 * MB);    // 8 MB
  u16* kp   = (u16*)(ws + 17 * MB);   // 8 MB
  u16* vp   = (u16*)(ws + 25 * MB);   // 8 MB (reused as out0 after transpose)
  u16* vpT  = (u16*)(ws + 33 * MB);   // 8 MB [H][N]
  u16* Pf   = (u16*)(ws + 41 * MB);   // 128 MB fp16 probabilities
  u16* out0 = vp;

  const bool usePf = ws_size >= 41 * MB + (size_t)N * N * 2;

  dim3 blk(256);

  // q projection
  k_cvt16<<<4096, blk, 0, stream>>>(q, xh, (N * H) / 4);
  k_cvt16<<<256, blk, 0, stream>>>(Wq, wb, (H * H) / 4);
  k_gemm<64, false, 1, true><<<dim3(64, 8), blk, 0, stream>>>(
      xh, wb, bq, qp, H, H, H, H);

  // k projection
  k_cvt16<<<4096, blk, 0, stream>>>(kin, xh, (N * H) / 4);
  k_cvt16<<<256, blk, 0, stream>>>(Wk, wb, (H * H) / 4);
  k_gemm<64, false, 1, true><<<dim3(64, 8), blk, 0, stream>>>(
      xh, wb, bk, kp, H, H, H, H);

  // v projection -> vp, then transpose -> vpT
  k_cvt16<<<4096, blk, 0, stream>>>(v, xh, (N * H) / 4);
  k_cvt16<<<256, blk, 0, stream>>>(Wv, wb, (H * H) / 4);
  k_gemm<64, false, 1, true><<<dim3(64, 8), blk, 0, stream>>>(
      xh, wb, bv, vp, H, H, H, H);
  k_transpose<<<dim3(128, 8), blk, 0, stream>>>(vp, vpT, N, H);

  // logits = qp @ kp^T  (fp32 out into normalized region)
  k_gemm<128, false, 0, false><<<dim3(64, 64), blk, 0, stream>>>(
      qp, kp, nullptr, norm, H, H, H, N);

  // softmax rows in place (+ fp16 copy for the AV GEMM)
  if (usePf)
    k_softmax<true><<<N, blk, 0, stream>>>(norm, Pf);
  else
    k_softmax<false><<<N, blk, 0, stream>>>(norm, nullptr);

  // out0 = normalized @ vp
  if (usePf)
    k_gemm<64, false, 1, false><<<dim3(64, 8), blk, 0, stream>>>(
        Pf, vpT, nullptr, out0, N, N, N, H);
  else
    k_gemm<64, true, 1, false><<<dim3(64, 8), blk, 0, stream>>>(
        norm, vpT, nullptr, out0, N, N, N, H);

  // out = out0 @ Wo^T + bo
  k_cvt16<<<256, blk, 0, stream>>>(Wo, wb, (H * H) / 4);
  k_gemm<64, false, 0, true><<<dim3(64, 8), blk, 0, stream>>>(
      out0, wb, bo, out, H, H, H, H);
}